// Round 3
// baseline (180.343 us; speedup 1.0000x reference)
//
#include <hip/hip_runtime.h>
#include <stdint.h>

#define B_ 2
#define S_ 2048
#define E_ 1024
#define H_ 16
#define D_ 64
#define R_ 16

typedef short s16x8 __attribute__((ext_vector_type(8)));
typedef float f32x4 __attribute__((ext_vector_type(4)));

#define K1_ 0.045084220027780106f   // log2(e)/32
#define K0_ -28.853900817779268f    // -20*log2(e)

// fp32 -> bf16 bits, round-to-nearest (ties away)
__device__ __forceinline__ unsigned short f2bf(float f) {
  union { float f; unsigned u; } v; v.f = f;
  return (unsigned short)((v.u + 0x8000u) >> 16);
}

// async global->LDS, 16B per lane
__device__ __forceinline__ void load_lds16(const void* g, void* l) {
  __builtin_amdgcn_global_load_lds(
      (__attribute__((address_space(1))) void*)(g),
      (__attribute__((address_space(3))) void*)(l), 16, 0, 0);
}

// ---------------- unified prep kernel ----------------
// blocks [0,4096): x fp32->bf16
// blocks [4096,4608): Wq/Wk transpose -> Wt[(which,h,d),e]  (Wq scaled by K1)
// blocks [4608,8704): fused Wv = Wvd@Wvu -> Wt[(2,h,d),e]
// blocks [8704,8716): biases (bq scaled by K1)
__global__ void k_prep(const float* __restrict__ x,
                       const float* __restrict__ Wq, const float* __restrict__ Wk,
                       const float* __restrict__ Wvd, const float* __restrict__ Wvu,
                       const float* __restrict__ bq, const float* __restrict__ bk,
                       const float* __restrict__ bvd, const float* __restrict__ bvu,
                       unsigned short* __restrict__ xb, unsigned short* __restrict__ Wt,
                       float* __restrict__ ball) {
  __shared__ float T[64][65];
  const int blk = blockIdx.x;
  const int t = threadIdx.x;
  if (blk < 4096) {
    int i = (blk * 256 + t) * 4;
    float4 v = *(const float4*)(x + i);
    ushort4 o;
    o.x = f2bf(v.x); o.y = f2bf(v.y); o.z = f2bf(v.z); o.w = f2bf(v.w);
    *(ushort4*)(xb + i) = o;
  } else if (blk < 4608) {
    const int bb = blk - 4096;
    const int which = bb >> 8;
    const int h = (bb >> 4) & 15;
    const int et = bb & 15;
    const float scl = which ? 1.f : K1_;
    const float* src = (which ? Wk : Wq) + (h * E_ + et * 64) * D_;
#pragma unroll
    for (int pr = 0; pr < 4; ++pr) {
      const int row = pr * 16 + (t >> 4);
      const int col = (t & 15) * 4;
      float4 v = *(const float4*)(src + row * 64 + col);
      T[row][col] = v.x; T[row][col + 1] = v.y; T[row][col + 2] = v.z; T[row][col + 3] = v.w;
    }
    __syncthreads();
#pragma unroll
    for (int pr = 0; pr < 4; ++pr) {
      const int d = pr * 16 + (t >> 4);
      const int ec = (t & 15) * 4;
      ushort4 o;
      o.x = f2bf(T[ec][d] * scl); o.y = f2bf(T[ec + 1][d] * scl);
      o.z = f2bf(T[ec + 2][d] * scl); o.w = f2bf(T[ec + 3][d] * scl);
      *(ushort4*)(Wt + ((which << 10) + h * 64 + d) * 1024 + et * 64 + ec) = o;
    }
  } else if (blk < 8704) {
    const int idx = (blk - 4608) * 256 + t;  // 1M
    const int row = idx >> 10;                // h*64+d
    const int e = idx & 1023;
    const int h = row >> 6, d = row & 63;
    const float4* wd4 = (const float4*)(Wvd + (h << 14) + e * 16);
    const float* wu = Wvu + h * R_ * D_ + d;
    float acc = 0.f;
#pragma unroll
    for (int r4 = 0; r4 < 4; ++r4) {
      float4 a = wd4[r4];
      acc += a.x * wu[(r4 * 4 + 0) * 64];
      acc += a.y * wu[(r4 * 4 + 1) * 64];
      acc += a.z * wu[(r4 * 4 + 2) * 64];
      acc += a.w * wu[(r4 * 4 + 3) * 64];
    }
    Wt[(2048 + row) * 1024 + e] = f2bf(acc);
  } else {
    int n = (blk - 8704) * 256 + t;  // 3072
    int which = n >> 10;
    int hd = n & 1023;
    int h = hd >> 6, d = hd & 63;
    float v;
    if (which == 0) v = bq[hd] * K1_;
    else if (which == 1) v = bk[hd];
    else {
      v = bvu[hd];
#pragma unroll
      for (int r = 0; r < R_; ++r) v += bvd[h * R_ + r] * Wvu[(h * R_ + r) * D_ + d];
    }
    ball[n] = v;
  }
}

// ---------------- fused QKV GEMM (proven structure, untouched) ----------------
// cols [0,1024): Q*K1 -> (bh, s, d); [1024,2048): K -> (bh, s, d);
// [2048,3072): V -> transposed (bh, d, s)

__global__ __launch_bounds__(256, 2) void k_gemm_qkv(
    const unsigned short* __restrict__ X, const unsigned short* __restrict__ Wt,
    const float* __restrict__ ball,
    unsigned short* __restrict__ Qb, unsigned short* __restrict__ Kb,
    unsigned short* __restrict__ Vb) {
  __shared__ unsigned short As[128 * 32];
  __shared__ unsigned short Bs[128 * 32];
  const int tid = threadIdx.x;
  const int lane = tid & 63, wave = tid >> 6;
  const int quad = lane >> 4, l16 = lane & 15;
  const int mBase = blockIdx.y * 128, nBase = blockIdx.x * 128;
  const int wm = (wave & 1) * 64, wn = (wave >> 1) * 64;
  const int lrow = lane >> 2, lcol = (lane & 3) * 8;

  f32x4 acc[4][4];
#pragma unroll
  for (int mi = 0; mi < 4; ++mi)
#pragma unroll
    for (int ni = 0; ni < 4; ++ni) acc[mi][ni] = (f32x4){0.f, 0.f, 0.f, 0.f};

  for (int k0 = 0; k0 < E_; k0 += 32) {
#pragma unroll
    for (int i = 0; i < 2; ++i) {
      const int r0 = __builtin_amdgcn_readfirstlane((wave + i * 4) * 16);
      load_lds16(X + (mBase + r0 + lrow) * E_ + k0 + lcol, &As[r0 * 32]);
      load_lds16(Wt + (nBase + r0 + lrow) * E_ + k0 + lcol, &Bs[r0 * 32]);
    }
    __syncthreads();
    s16x8 af[4], bfr[4];
#pragma unroll
    for (int mi = 0; mi < 4; ++mi)
      af[mi] = *(const s16x8*)&As[(wm + mi * 16 + l16) * 32 + quad * 8];
#pragma unroll
    for (int ni = 0; ni < 4; ++ni)
      bfr[ni] = *(const s16x8*)&Bs[(wn + ni * 16 + l16) * 32 + quad * 8];
#pragma unroll
    for (int mi = 0; mi < 4; ++mi)
#pragma unroll
      for (int ni = 0; ni < 4; ++ni)
        acc[mi][ni] = __builtin_amdgcn_mfma_f32_16x16x32_bf16(af[mi], bfr[ni], acc[mi][ni], 0, 0, 0);
    __syncthreads();
  }

  const int which = nBase >> 10;  // uniform per block
#pragma unroll
  for (int ni = 0; ni < 4; ++ni) {
    const int n = nBase + wn + ni * 16 + l16;
    const int nh = n & 1023;
    const int h = nh >> 6, d = nh & 63;
    const float bias = ball[n];
#pragma unroll
    for (int mi = 0; mi < 4; ++mi) {
      const int m0 = mBase + wm + mi * 16 + quad * 4;
      const int b = m0 >> 11;
      const int s = m0 & 2047;
      const int bh = b * H_ + h;
      if (which == 2) {
        ushort4 pk;
        pk.x = f2bf(acc[mi][ni][0] + bias);
        pk.y = f2bf(acc[mi][ni][1] + bias);
        pk.z = f2bf(acc[mi][ni][2] + bias);
        pk.w = f2bf(acc[mi][ni][3] + bias);
        *(ushort4*)(Vb + (bh * D_ + d) * S_ + s) = pk;  // transposed store
      } else {
        unsigned short* dst = (which == 0 ? Qb : Kb) + (bh * S_ + s) * D_ + d;
#pragma unroll
        for (int r = 0; r < 4; ++r) dst[r * D_] = f2bf(acc[mi][ni][r] + bias);
      }
    }
  }
}

// ---------------- flash attention (anti-causal: attend t >= s) ----------------
// R3: two multiplicative LDS-pipe levers on top of R0's PROVEN dataflow
// (mfma(Q,K), Ps per-wave LDS P-route, elementwise diag mask, per-quad l):
//  1. QBLK=128: each wave owns 2 q-groups (g=0,1); K/V frags read once per
//     tile feed both groups -> LDS reads per MFMA halved. Grid 512 blocks
//     (2/CU), chunk-paired so every CU gets 34 tile-units.
//  2. XOR-swizzled Ks/Vs (T2, rule #21): storage chunk3' = chunk3 ^ ((row>>1)&7)
//     within each 128B row-pair. ds_read_b128 bank-groups become uniform
//     (2 lanes/group in a 16-lane window = free). global_load_lds dest stays
//     LINEAR; the global SOURCE address is the inverse permutation (per-lane
//     constants sr16/sc). Read-side term folds into per-lane constant rbase.
__global__ __launch_bounds__(256, 2) void k_attn(
    const unsigned short* __restrict__ Qb, const unsigned short* __restrict__ Kb,
    const unsigned short* __restrict__ Vb, float* __restrict__ out) {
  __shared__ unsigned short Ks[2][2 * 64 * 32];   // [buf][dhalf][64 k][32 d] (swizzled)
  __shared__ unsigned short Vs[2][2 * 64 * 32];   // [buf][thalf][64 d][32 t] (swizzled)
  __shared__ unsigned short Ps[4][32][40];        // [wave][q-row 0..31][32 t + pad]
  const int tid = threadIdx.x;
  const int lane = tid & 63, wave = tid >> 6;
  const int quad = lane >> 4, l16 = lane & 15;
  const int chunk = blockIdx.x >> 8;
  const int j = blockIdx.x & 255;
  int qt = j >> 5;                       // 0..7
  if (chunk) qt = 15 - qt;               // chunk pairing: 34 tile-units per CU
  const int bh = j & 31;
  const int q0 = qt * 128;
  const int r0 = __builtin_amdgcn_readfirstlane(wave * 16);
  const f32x4 kvec = {K0_, K0_, K0_, K0_};

  // DMA source swizzle (per-lane constants; inverse of read-side XOR)
  const int lrow = lane >> 2;                          // LDS slot row (within 16)
  const int q3w  = ((lrow & 1) << 2) | (lane & 3);     // slot chunk3 within 128B pair
  const int q3e  = q3w ^ ((lrow >> 1) & 7);            // element chunk3 stored here
  const int sr16 = (lrow & ~1) | (q3e >> 2);           // source row (within 16)
  const int sc   = (q3e & 3) * 8;                      // source col (elements)

  // read-side swizzled lane offset (elements, within one 4KB half):
  // element (row=blk*16+l16, chunk=quad) lives at pair*64 + (chunk3^((l16>>1)&7))*8
  const int rbase = (l16 >> 1) * 64 + ((((l16 & 1) << 2) | quad) ^ ((l16 >> 1) & 7)) * 8;

  s16x8 qf[2][2];
#pragma unroll
  for (int g = 0; g < 2; ++g) {
    const unsigned short* qp = Qb + (bh * S_ + q0 + g * 64 + wave * 16 + l16) * D_ + quad * 8;
    qf[g][0] = *(const s16x8*)qp;
    qf[g][1] = *(const s16x8*)(qp + 32);
  }
  f32x4 o[2][4];
  float l_acc[2][4];
#pragma unroll
  for (int g = 0; g < 2; ++g)
#pragma unroll
    for (int dc = 0; dc < 4; ++dc) {
      o[g][dc] = (f32x4){0.f, 0.f, 0.f, 0.f};
      l_acc[g][dc] = 0.f;
    }

#define DMA_KV(kt_, b_)                                                           \
  {                                                                               \
    _Pragma("unroll")                                                             \
    for (int hdc = 0; hdc < 2; ++hdc) {                                           \
      load_lds16(Kb + (bh * S_ + (kt_) * 64 + r0 + sr16) * D_ + hdc * 32 + sc,    \
                 &Ks[b_][hdc * 2048 + r0 * 32]);                                  \
      load_lds16(Vb + (bh * D_ + r0 + sr16) * S_ + (kt_) * 64 + hdc * 32 + sc,    \
                 &Vs[b_][hdc * 2048 + r0 * 32]);                                  \
    }                                                                             \
  }

  // prologue: stage tile 2*qt into buffer 0
  DMA_KV(2 * qt, 0);

  int buf = 0;
  for (int kt = 2 * qt; kt < S_ / 64; ++kt) {
    __syncthreads();  // Ks/Vs[buf] DMA drained; prior reads of buf^1 done
    if (kt + 1 < S_ / 64) DMA_KV(kt + 1, buf ^ 1);

    const bool diag = (kt < 2 * qt + 2);
#pragma unroll
    for (int kc = 0; kc < 2; ++kc) {
      // K fragments for this 32-t half, shared by both q-groups
      s16x8 kf[2][2];
#pragma unroll
      for (int tcc = 0; tcc < 2; ++tcc)
#pragma unroll
        for (int hdc = 0; hdc < 2; ++hdc)
          kf[tcc][hdc] = *(const s16x8*)&Ks[buf][hdc * 2048 + (kc * 2 + tcc) * 512 + rbase];
#pragma unroll
      for (int g = 0; g < 2; ++g) {
#pragma unroll
        for (int tcc = 0; tcc < 2; ++tcc) {
          const int tc = kc * 2 + tcc;
          f32x4 a = __builtin_amdgcn_mfma_f32_16x16x32_bf16(qf[g][0], kf[tcc][0], kvec, 0, 0, 0);
          f32x4 sc4 = __builtin_amdgcn_mfma_f32_16x16x32_bf16(qf[g][1], kf[tcc][1], a, 0, 0, 0);
          if (diag) {
            const int t = kt * 64 + tc * 16 + l16;
            const int q = q0 + g * 64 + wave * 16 + quad * 4;
#pragma unroll
            for (int r = 0; r < 4; ++r)
              if (t < q + r) sc4[r] = -200.f;
          }
#pragma unroll
          for (int r = 0; r < 4; ++r) {
            float p = exp2f(sc4[r]);
            l_acc[g][r] += p;
            Ps[wave][g * 16 + quad * 4 + r][tcc * 16 + l16] =
                (unsigned short)(__float_as_uint(p) >> 16);
          }
        }
      }
      // PV: per-wave Ps (no barrier); V frags shared by both q-groups
      s16x8 pf0 = *(const s16x8*)&Ps[wave][l16][quad * 8];
      s16x8 pf1 = *(const s16x8*)&Ps[wave][16 + l16][quad * 8];
#pragma unroll
      for (int dc = 0; dc < 4; ++dc) {
        s16x8 vb = *(const s16x8*)&Vs[buf][kc * 2048 + dc * 512 + rbase];
        o[0][dc] = __builtin_amdgcn_mfma_f32_16x16x32_bf16(pf0, vb, o[0][dc], 0, 0, 0);
        o[1][dc] = __builtin_amdgcn_mfma_f32_16x16x32_bf16(pf1, vb, o[1][dc], 0, 0, 0);
      }
    }
    buf ^= 1;
  }
#undef DMA_KV

  // epilogue: reduce l over the 16 lanes holding each row's t-slices
#pragma unroll
  for (int off = 1; off < 16; off <<= 1)
#pragma unroll
    for (int g = 0; g < 2; ++g)
#pragma unroll
      for (int r = 0; r < 4; ++r) l_acc[g][r] += __shfl_xor(l_acc[g][r], off);
  float rinv[2][4];
#pragma unroll
  for (int g = 0; g < 2; ++g)
#pragma unroll
    for (int r = 0; r < 4; ++r) rinv[g][r] = 1.f / l_acc[g][r];

  const int b = bh >> 4, h = bh & 15;
#pragma unroll
  for (int g = 0; g < 2; ++g)
#pragma unroll
    for (int dc = 0; dc < 4; ++dc)
#pragma unroll
      for (int r = 0; r < 4; ++r) {
        const int s = q0 + g * 64 + wave * 16 + quad * 4 + r;
        out[(b * S_ + s) * (H_ * D_) + h * D_ + dc * 16 + l16] = o[g][dc][r] * rinv[g][r];
      }
}

// ---------------- launch ----------------

extern "C" void kernel_launch(void* const* d_in, const int* in_sizes, int n_in,
                              void* d_out, int out_size, void* d_ws, size_t ws_size,
                              hipStream_t stream) {
  const float* x   = (const float*)d_in[0];
  const float* Wq  = (const float*)d_in[1];
  const float* bq  = (const float*)d_in[2];
  const float* Wk  = (const float*)d_in[3];
  const float* bk  = (const float*)d_in[4];
  const float* Wvd = (const float*)d_in[5];
  const float* bvd = (const float*)d_in[6];
  const float* Wvu = (const float*)d_in[7];
  const float* bvu = (const float*)d_in[8];
  float* out = (float*)d_out;

  char* ws = (char*)d_ws;
  unsigned short* xb   = (unsigned short*)(ws);                    // 8 MB
  unsigned short* Wt   = (unsigned short*)(ws + (8u << 20));       // 6 MB
  float*          ball = (float*)(ws + (14u << 20));               // 12 KB
  unsigned short* Qb   = (unsigned short*)(ws + (15u << 20));      // 8 MB
  unsigned short* Kb   = (unsigned short*)(ws + (23u << 20));      // 8 MB
  unsigned short* Vb   = (unsigned short*)(ws + (31u << 20));      // 8 MB (transposed)

  k_prep<<<8716, 256, 0, stream>>>(x, Wq, Wk, Wvd, Wvu, bq, bk, bvd, bvu, xb, Wt, ball);
  k_gemm_qkv<<<dim3(3072 / 128, 4096 / 128), 256, 0, stream>>>(xb, Wt, ball, Qb, Kb, Vb);
  k_attn<<<512, 256, 0, stream>>>(Qb, Kb, Vb, out);
}